// Round 14
// baseline (2862.831 us; speedup 1.0000x reference)
//
#include <hip/hip_runtime.h>
#include <math.h>

#define CCH  128
#define HW   32
#define OCT  8        // out channels per block (halves DS + s_load per FMA)
#define NPH  32       // 1 input channel per phase per K-slice
#define PSW  36       // padded row stride
#define PPL  1296     // padded plane 36x36
#define SLAB 432      // 12-row slab (8 px rows + 4 halo) x 36, CONTIGUOUS in padded plane

// Block = 1024 thr = 16 waves = 4 K-slices x 4 row-groups; full 32x32 plane,
// 8 oc per block; grid 16 ocg x 16 b = 256 blocks (1/CU, 16 waves/CU).
// Conv inputs pre-padded [B,C,36,36] in ws (borders zeroed once): EPI0 RMWs
// mem_post there (pad0), EPI1 writes spikes there (pad1) + normal d_out.
// Staging: wave-private 12-row slab = 2 global_load_lds chunks (contiguous,
// zero staging VALU/VGPR), double-buffered, counted s_waitcnt vmcnt(2)
// (+sched_barrier fence) -- ZERO barriers in the K-loop. Per (ic,kh):
// 2 ds_read_b128 feed 8oc x 5kw x 4px = 320 FMA cyc -> DS pipe ~0.3 of FMA.
// Weights via readfirstlane'd slice index -> provably uniform -> s_load.
// 6 one-time barriers for the 4-way K-slice tree reduce (LDS stride 17).
__device__ __forceinline__ void gll16(const float* g, float* l) {
    __builtin_amdgcn_global_load_lds(
        (const __attribute__((address_space(1))) unsigned int*)g,
        (__attribute__((address_space(3))) unsigned int*)l, 16, 0, 0);
}

template<int EPI>
__global__ __launch_bounds__(1024, 4) void lif_conv(
    const float* __restrict__ cpad,  // padded conv input [B,C,1296]
    const float* __restrict__ wgt,   // [C,C,5,5] OIHW
    const float* __restrict__ bias,  // [C]
    const float* __restrict__ xin,   // EPI0: x_t (normal layout); EPI1 unused
    float* __restrict__ pad0,        // mem_post padded (EPI0 RMW, EPI1 read)
    float* __restrict__ outn,        // EPI1: spikes, normal layout (d_out)
    float* __restrict__ pad1,        // EPI1: spikes, padded copy
    int first)
{
    const int ocg  = blockIdx.x;         // 0..15
    const int b    = blockIdx.y;         // 0..15
    const int oc0  = ocg * OCT;
    const int tid  = threadIdx.x;
    const int w    = tid >> 6;           // wave 0..15
    const int lane = tid & 63;
    const int ks   = w >> 2;             // K-slice 0..3 (32 ics each)
    const int rg   = w & 3;              // row-group 0..3 (8 px rows each)
    const int rl   = lane >> 3;          // 0..7 px row within wave
    const int cl   = (lane & 7) * 4;     // col base, 4 px/thread

    const int sw  = __builtin_amdgcn_readfirstlane(w);
    const int sks = sw >> 2;             // scalar K-slice (weights, DMA base)
    const int srg = sw & 3;              // scalar row-group (DMA base)

    __shared__ __align__(16) float s_in[16 * 2 * SLAB];   // 55296 B

    float acc[OCT][4];
#pragma unroll
    for (int oc = 0; oc < OCT; ++oc)
#pragma unroll
        for (int j = 0; j < 4; ++j) acc[oc][j] = 0.f;

    if (!(EPI == 0 && first)) {
        // wave-private DMA source: slab = padded rows rg*8 .. rg*8+11 (contiguous)
        const float* pbase = cpad + ((size_t)b * CCH + sks * 32) * PPL + srg * 288;
        float* bufA = s_in + sw * (2 * SLAB);
        float* bufB = bufA + SLAB;

        auto STAGE = [&](int ph, float* dst) {
            const float* ps = pbase + (size_t)ph * PPL;
            gll16(ps + lane * 4, dst);                       // floats 0..255
            if (lane < 44) gll16(ps + 256 + lane * 4, dst + 256); // 256..431
        };
        auto COMPUTE = [&](int ph, const float* tin) {
            float win[5][8];
#pragma unroll
            for (int kh = 0; kh < 5; ++kh) {
                const float* src = tin + (rl + kh) * PSW + cl;
                float4 a = *(const float4*)src;
                float4 c = *(const float4*)(src + 4);
                win[kh][0] = a.x; win[kh][1] = a.y; win[kh][2] = a.z; win[kh][3] = a.w;
                win[kh][4] = c.x; win[kh][5] = c.y; win[kh][6] = c.z; win[kh][7] = c.w;
            }
            const float* wb = wgt + ((size_t)oc0 * CCH + sks * 32 + ph) * 25;
#pragma unroll
            for (int oc = 0; oc < OCT; ++oc) {
                const float* wo = wb + oc * (CCH * 25);
#pragma unroll
                for (int kh = 0; kh < 5; ++kh) {
#pragma unroll
                    for (int kw = 0; kw < 5; ++kw) {
                        float wv = wo[kh * 5 + kw];   // SGPR-uniform -> s_load
                        acc[oc][0] += win[kh][kw]     * wv;
                        acc[oc][1] += win[kh][kw + 1] * wv;
                        acc[oc][2] += win[kh][kw + 2] * wv;
                        acc[oc][3] += win[kh][kw + 3] * wv;
                    }
                }
            }
        };

        STAGE(0, bufA);
        for (int ph = 0; ph < NPH; ph += 2) {
            STAGE(ph + 1, bufB);                  // ph+1 <= 31 always
            asm volatile("s_waitcnt vmcnt(2)" ::: "memory");   // drain bufA's 2
            __builtin_amdgcn_sched_barrier(0);
            COMPUTE(ph, bufA);
            if (ph + 2 < NPH) {
                STAGE(ph + 2, bufA);
                asm volatile("s_waitcnt vmcnt(2)" ::: "memory"); // drain bufB's 2
            } else {
                asm volatile("s_waitcnt vmcnt(0)" ::: "memory");
            }
            __builtin_amdgcn_sched_barrier(0);
            COMPUTE(ph + 1, bufB);
        }

        // ---- 4-way K-slice tree reduce (only barriers in the kernel) ----
        __syncthreads();
        const int key = (rg * 64 + lane) * 17;
        float* A = s_in;            // 4352 floats
        float* B = s_in + 4352;
        if (ks == 3)
#pragma unroll
            for (int oc = 0; oc < 4; ++oc)
#pragma unroll
                for (int j = 0; j < 4; ++j) A[key + oc * 4 + j] = acc[oc][j];
        if (ks == 2)
#pragma unroll
            for (int oc = 0; oc < 4; ++oc)
#pragma unroll
                for (int j = 0; j < 4; ++j) B[key + oc * 4 + j] = acc[oc][j];
        __syncthreads();
        if (ks == 1)
#pragma unroll
            for (int oc = 0; oc < 4; ++oc)
#pragma unroll
                for (int j = 0; j < 4; ++j) acc[oc][j] += A[key + oc * 4 + j];
        if (ks == 0)
#pragma unroll
            for (int oc = 0; oc < 4; ++oc)
#pragma unroll
                for (int j = 0; j < 4; ++j) acc[oc][j] += B[key + oc * 4 + j];
        __syncthreads();
        if (ks == 3)
#pragma unroll
            for (int oc = 4; oc < 8; ++oc)
#pragma unroll
                for (int j = 0; j < 4; ++j) A[key + (oc - 4) * 4 + j] = acc[oc][j];
        if (ks == 2)
#pragma unroll
            for (int oc = 4; oc < 8; ++oc)
#pragma unroll
                for (int j = 0; j < 4; ++j) B[key + (oc - 4) * 4 + j] = acc[oc][j];
        __syncthreads();
        if (ks == 1)
#pragma unroll
            for (int oc = 4; oc < 8; ++oc)
#pragma unroll
                for (int j = 0; j < 4; ++j) acc[oc][j] += A[key + (oc - 4) * 4 + j];
        if (ks == 0)
#pragma unroll
            for (int oc = 4; oc < 8; ++oc)
#pragma unroll
                for (int j = 0; j < 4; ++j) acc[oc][j] += B[key + (oc - 4) * 4 + j];
        __syncthreads();
        if (ks == 1) {
#pragma unroll
            for (int oc = 0; oc < 4; ++oc)
#pragma unroll
                for (int j = 0; j < 4; ++j) {
                    A[key + oc * 4 + j] = acc[oc][j];
                    B[key + oc * 4 + j] = acc[oc + 4][j];
                }
        }
        __syncthreads();
        if (ks == 0)
#pragma unroll
            for (int oc = 0; oc < 4; ++oc)
#pragma unroll
                for (int j = 0; j < 4; ++j) {
                    acc[oc][j]     += A[key + oc * 4 + j];
                    acc[oc + 4][j] += B[key + oc * 4 + j];
                }
    }

    // ---- epilogue: fused LIF pointwise math, ks==0 waves ----
    if (ks == 0) {
        const int row = rg * 8 + rl;
#pragma unroll
        for (int oc = 0; oc < OCT; ++oc) {
            const size_t pidxn = (((size_t)b * CCH + oc0 + oc) * HW + row) * HW + cl;
            const size_t pidxp = ((size_t)b * CCH + oc0 + oc) * PPL + (row + 2) * PSW + 2 + cl;
            const float bia = bias[oc0 + oc];
            float y[4];
#pragma unroll
            for (int j = 0; j < 4; ++j) y[j] = acc[oc][j] + bia;
            if (EPI == 0) {
                float4 xv = *(const float4*)(xin + pidxn);
                float xr[4] = {xv.x, xv.y, xv.z, xv.w};
                float mo[4] = {0.f, 0.f, 0.f, 0.f};
                if (!first) {
                    float2 a = *(const float2*)(pad0 + pidxp);
                    float2 c = *(const float2*)(pad0 + pidxp + 2);
                    mo[0] = a.x; mo[1] = a.y; mo[2] = c.x; mo[3] = c.y;
                }
                float mp[4];
#pragma unroll
                for (int j = 0; j < 4; ++j) {
                    float mv = (mo[j] > 0.5f) ? 0.f : mo[j];   // reset-mem recompute
                    mp[j] = 0.2f * mv + (1.f / (1.f + expf(-y[j]))) * xr[j];
                }
                *(float2*)(pad0 + pidxp)     = make_float2(mp[0], mp[1]);
                *(float2*)(pad0 + pidxp + 2) = make_float2(mp[2], mp[3]);
            } else {
                float2 a = *(const float2*)(pad0 + pidxp);
                float2 c = *(const float2*)(pad0 + pidxp + 2);
                float m[4] = {a.x, a.y, c.x, c.y};
                float sp[4];
#pragma unroll
                for (int j = 0; j < 4; ++j) {
                    float g = (y[j] > 0.f) ? 1.f : ((y[j] < 0.f) ? -1.f : 0.f);
                    float s = (m[j] > 0.5f) ? 1.f : 0.f;
                    sp[j] = g * s;
                }
                *(float4*)(outn + pidxn) = make_float4(sp[0], sp[1], sp[2], sp[3]);
                *(float2*)(pad1 + pidxp)     = make_float2(sp[0], sp[1]);
                *(float2*)(pad1 + pidxp + 2) = make_float2(sp[2], sp[3]);
            }
        }
    }
}

extern "C" void kernel_launch(void* const* d_in, const int* in_sizes, int n_in,
                              void* d_out, int out_size, void* d_ws, size_t ws_size,
                              hipStream_t stream) {
    const float* x      = (const float*)d_in[0];  // [8,16,128,32,32]
    const float* back_w = (const float*)d_in[1];  // [128,128,5,5]
    const float* back_b = (const float*)d_in[2];  // [128]
    const float* ei_w   = (const float*)d_in[3];
    const float* ei_b   = (const float*)d_in[4];
    float* out = (float*)d_out;                   // [8,16,128,32,32] spikes

    const size_t N     = (size_t)16 * CCH * HW * HW;   // 2,097,152
    const size_t PADSZ = (size_t)16 * CCH * PPL;       // 2,654,208
    float* pad0 = (float*)d_ws;           // mem_post padded
    float* pad1 = pad0 + PADSZ;           // spikes padded

    // borders stay zero forever; interiors fully rewritten each step
    hipMemsetAsync(d_ws, 0, 2 * PADSZ * sizeof(float), stream);

    dim3 grid(CCH / OCT, 16);             // (16, 16) = 256 blocks
    for (int t = 0; t < 8; ++t) {
        lif_conv<0><<<grid, 1024, 0, stream>>>(
            pad1, back_w, back_b,
            x + (size_t)t * N,
            pad0, nullptr, nullptr, (t == 0) ? 1 : 0);
        lif_conv<1><<<grid, 1024, 0, stream>>>(
            pad0, ei_w, ei_b,
            nullptr,
            pad0, out + (size_t)t * N, pad1, 0);
    }
}